// Round 5
// baseline (766.065 us; speedup 1.0000x reference)
//
#include <hip/hip_runtime.h>
#include <math.h>

// GATNet_MLP R5: R4 + (a) GEMM tile 128x128 (2x2 waves, better MFMA:staging ratio),
// (b) gat_agg: packed int2 CSR + 2x unrolled edge loop (two gathers in flight).

#define N_NODES 50000
#define N_EDGES 400000
#define N_GRAPH 64
#define DIN     128
#define NHC     256
#define DOUT    32

typedef _Float16 f16x8 __attribute__((ext_vector_type(8)));
typedef _Float16 f16x4 __attribute__((ext_vector_type(4)));
typedef float    f32x4 __attribute__((ext_vector_type(4)));

#define LDP 40   // padded LDS row stride in halfs (80B; kills b128 bank conflicts - R4 verified)

// ================= fp16x2-split MFMA GEMM, 128x128 tile =================
// A planes [nrow][K], B planes [Npad][K] transposed. Npad >= gridX*128.
// mode 0: C fp32 [nrow][256] (no bias) ; mode 1: bias+gelu -> fp16 planes ;
// mode 2: bias -> fp32 C [nrow][ncols] (cols masked)
__global__ __launch_bounds__(256) void mfma_gemm_kernel(
    const _Float16* __restrict__ Ah, const _Float16* __restrict__ Al,
    const _Float16* __restrict__ Bh, const _Float16* __restrict__ Bl,
    const float* __restrict__ bias, float* __restrict__ C,
    _Float16* __restrict__ Oh, _Float16* __restrict__ Ol,
    int nrow, int K, int ncols, int mode)
{
    __shared__ __align__(16) _Float16 sAh[128][LDP];
    __shared__ __align__(16) _Float16 sAl[128][LDP];
    __shared__ __align__(16) _Float16 sBh[128][LDP];
    __shared__ __align__(16) _Float16 sBl[128][LDP];

    const int tid = threadIdx.x, lane = tid & 63, wid = tid >> 6;
    const int wm = wid & 1, wn = wid >> 1;

    // XCD-aware swizzle (gridX==2): bids k and k+8 (same XCD slot mod 8) are the
    // two col-tiles of one row-block -> A row-block stays in that XCD's L2.
    int xt, yt;
    if (gridDim.x == 2) {
        int bid = blockIdx.x + (blockIdx.y << 1);
        yt = (bid >> 4) * 8 + (bid & 7);
        xt = (bid >> 3) & 1;
    } else { xt = blockIdx.x; yt = blockIdx.y; }
    const int row0 = yt * 128, col0 = xt * 128;
    if (row0 >= nrow) return;                 // uniform across block (grid Y padded %8)

    const int frow = lane & 15, fk = (lane >> 4) * 8;

    f32x4 acc[4][4] = {};

    for (int k0 = 0; k0 < K; k0 += 32) {
        // stage A and B: 128 rows x 32 halfs per plane = 512 f16x8 chunks; 2/thread
#pragma unroll
        for (int pass = 0; pass < 2; pass++) {
            int idx = tid + pass * 256;       // 0..511
            int r = idx >> 2, kq = idx & 3;
            int gr = row0 + r;
            long goA = (long)gr * K + k0 + kq * 8;
            f16x8 vh = (gr < nrow) ? *(const f16x8*)(Ah + goA) : (f16x8)0;
            f16x8 vl = (gr < nrow) ? *(const f16x8*)(Al + goA) : (f16x8)0;
            *(f16x8*)&sAh[r][kq * 8] = vh;
            *(f16x8*)&sAl[r][kq * 8] = vl;
            long goB = (long)(col0 + r) * K + k0 + kq * 8;
            *(f16x8*)&sBh[r][kq * 8] = *(const f16x8*)(Bh + goB);
            *(f16x8*)&sBl[r][kq * 8] = *(const f16x8*)(Bl + goB);
        }
        __syncthreads();

        f16x8 bh[4], bl[4];
#pragma unroll
        for (int nt = 0; nt < 4; nt++) {
            bh[nt] = *(const f16x8*)&sBh[wn * 64 + nt * 16 + frow][fk];
            bl[nt] = *(const f16x8*)&sBl[wn * 64 + nt * 16 + frow][fk];
        }
#pragma unroll
        for (int mt = 0; mt < 4; mt++) {
            f16x8 ah = *(const f16x8*)&sAh[wm * 64 + mt * 16 + frow][fk];
            f16x8 al = *(const f16x8*)&sAl[wm * 64 + mt * 16 + frow][fk];
#pragma unroll
            for (int nt = 0; nt < 4; nt++) {
                acc[mt][nt] = __builtin_amdgcn_mfma_f32_16x16x32_f16(ah, bh[nt], acc[mt][nt], 0, 0, 0);
                acc[mt][nt] = __builtin_amdgcn_mfma_f32_16x16x32_f16(ah, bl[nt], acc[mt][nt], 0, 0, 0);
                acc[mt][nt] = __builtin_amdgcn_mfma_f32_16x16x32_f16(al, bh[nt], acc[mt][nt], 0, 0, 0);
            }
        }
        __syncthreads();
    }

    // epilogue: C/D layout col=lane&15, row=(lane>>4)*4+reg
    const int crow0 = row0 + wm * 64 + (lane >> 4) * 4;
    const int ccol0 = col0 + wn * 64 + (lane & 15);
#pragma unroll
    for (int mt = 0; mt < 4; mt++) {
#pragma unroll
        for (int nt = 0; nt < 4; nt++) {
            int col = ccol0 + nt * 16;
#pragma unroll
            for (int r = 0; r < 4; r++) {
                int row = crow0 + mt * 16 + r;
                if (row >= nrow) continue;
                float v = acc[mt][nt][r];
                if (mode == 0) {
                    C[(long)row * 256 + col] = v;
                } else if (mode == 1) {
                    v += bias[col];
                    v = 0.5f * v * (1.f + erff(v * 0.7071067811865475f));
                    _Float16 hh = (_Float16)v;
                    Oh[(long)row * 256 + col] = hh;
                    Ol[(long)row * 256 + col] = (_Float16)(v - (float)hh);
                } else {
                    if (col < ncols) {
                        v += bias[col];
                        C[(long)row * ncols + col] = v;
                    }
                }
            }
        }
    }
}

// -------- split fp32 -> fp16 hi/lo planes --------
__global__ __launch_bounds__(256) void split_kernel(
    const float* __restrict__ in, _Float16* __restrict__ oh, _Float16* __restrict__ ol, int n4)
{
    int i = blockIdx.x * 256 + threadIdx.x;
    if (i >= n4) return;
    float4 v = ((const float4*)in)[i];
    f16x4 h, l;
    h[0] = (_Float16)v.x; l[0] = (_Float16)(v.x - (float)h[0]);
    h[1] = (_Float16)v.y; l[1] = (_Float16)(v.y - (float)h[1]);
    h[2] = (_Float16)v.z; l[2] = (_Float16)(v.z - (float)h[2]);
    h[3] = (_Float16)v.w; l[3] = (_Float16)(v.w - (float)h[3]);
    *(f16x4*)(oh + (long)i * 4) = h;
    *(f16x4*)(ol + (long)i * 4) = l;
}

// -------- transpose + split weights: W[K][N] fp32 -> planes [Npad][K] --------
__global__ __launch_bounds__(256) void tsplit_kernel(
    const float* __restrict__ W, _Float16* __restrict__ Bh, _Float16* __restrict__ Bl,
    int K, int N, int Npad)
{
    int id = blockIdx.x * 256 + threadIdx.x;
    if (id >= Npad * K) return;
    int n = id / K, k = id - n * K;
    float v = (n < N) ? W[(long)k * N + n] : 0.f;
    _Float16 h = (_Float16)v;
    Bh[id] = h;
    Bl[id] = (_Float16)(v - (float)h);
}

// -------- per-node attention scalars --------
__global__ __launch_bounds__(256) void asd_kernel(
    const float* __restrict__ h, const float* __restrict__ atts, const float* __restrict__ attd,
    float* __restrict__ asb, float* __restrict__ adb, int total, int H, int C)
{
    int i = blockIdx.x * 256 + threadIdx.x;
    if (i >= total) return;
    int n = i / H, hh = i - n * H;
    const float4* hp = (const float4*)(h + (long)n * NHC + hh * C);
    const float4* sp = (const float4*)(atts + hh * C);
    const float4* dp = (const float4*)(attd + hh * C);
    float ss = 0.f, dd = 0.f;
    for (int c = 0; c < C / 4; c++) {
        float4 hv = hp[c], sv = sp[c], dv = dp[c];
        ss += hv.x * sv.x + hv.y * sv.y + hv.z * sv.z + hv.w * sv.w;
        dd += hv.x * dv.x + hv.y * dv.y + hv.z * dv.z + hv.w * dv.w;
    }
    asb[i] = ss; adb[i] = dd;
}

// -------- Me[j,h] = sum_c We[j, h*C+c] * ae[h*C+c] --------
__global__ void me_kernel(const float* __restrict__ We, const float* __restrict__ ae,
                          float* __restrict__ Me, int H, int C)
{
    int i = threadIdx.x;
    if (i >= 5 * H) return;
    int j = i / H, hh = i - j * H;
    float s = 0.f;
    for (int c = 0; c < C; c++) s += We[j * NHC + hh * C + c] * ae[hh * C + c];
    Me[i] = s;
}

// -------- edge-parallel p --------
__global__ __launch_bounds__(256) void edge_p_kernel(
    const int* __restrict__ ei, const float* __restrict__ ea,
    const float* __restrict__ asb, const float* __restrict__ adb,
    const float* __restrict__ Me, float* __restrict__ p, int E, int H)
{
    int e = blockIdx.x * 256 + threadIdx.x;
    if (e >= E) return;
    int src = ei[e], dst = ei[E + e];
    float a0 = ea[e * 5 + 0], a1 = ea[e * 5 + 1], a2 = ea[e * 5 + 2],
          a3 = ea[e * 5 + 3], a4 = ea[e * 5 + 4];
    for (int h = 0; h < H; h++) {
        float aeh = a0 * Me[0 * H + h] + a1 * Me[1 * H + h] + a2 * Me[2 * H + h]
                  + a3 * Me[3 * H + h] + a4 * Me[4 * H + h];
        float al = asb[src * H + h] + adb[dst * H + h] + aeh;
        al = fmaxf(al, 0.2f * al);
        p[(long)e * H + h] = expf(al);
    }
}

// ================= CSR build (entries packed int2{src,eid}) =================
__global__ __launch_bounds__(256) void count_kernel(
    const int* __restrict__ ei, int* __restrict__ deg, int E)
{
    int e = blockIdx.x * 256 + threadIdx.x;
    if (e < E) atomicAdd(&deg[ei[E + e]], 1);
}

__global__ __launch_bounds__(256) void scan_block_kernel(
    const int* __restrict__ deg, int* __restrict__ rowstart, int* __restrict__ partial, int n)
{
    __shared__ int s[256];
    int i = blockIdx.x * 256 + threadIdx.x;
    int v = (i < n) ? deg[i] : 0;
    s[threadIdx.x] = v;
    __syncthreads();
    for (int off = 1; off < 256; off <<= 1) {
        int t = (threadIdx.x >= off) ? s[threadIdx.x - off] : 0;
        __syncthreads();
        s[threadIdx.x] += t;
        __syncthreads();
    }
    if (i < n) rowstart[i] = s[threadIdx.x] - v;
    if (threadIdx.x == 255) partial[blockIdx.x] = s[255];
}

__global__ __launch_bounds__(256) void scan_partial_kernel(int* __restrict__ partial, int nb)
{
    __shared__ int s[256];
    int v = (threadIdx.x < nb) ? partial[threadIdx.x] : 0;
    s[threadIdx.x] = v;
    __syncthreads();
    for (int off = 1; off < 256; off <<= 1) {
        int t = (threadIdx.x >= off) ? s[threadIdx.x - off] : 0;
        __syncthreads();
        s[threadIdx.x] += t;
        __syncthreads();
    }
    if (threadIdx.x < nb) partial[threadIdx.x] = s[threadIdx.x] - v;
}

__global__ __launch_bounds__(256) void scan_add_kernel(
    int* __restrict__ rowstart, const int* __restrict__ partial, int* __restrict__ cursor,
    int n, int E)
{
    int i = blockIdx.x * 256 + threadIdx.x;
    if (i < n) {
        int v = rowstart[i] + partial[blockIdx.x];
        rowstart[i] = v;
        cursor[i] = v;
    }
    if (i == 0) rowstart[n] = E;
}

__global__ __launch_bounds__(256) void fill_kernel(
    const int* __restrict__ ei, int* __restrict__ cursor, int2* __restrict__ csr, int E)
{
    int e = blockIdx.x * 256 + threadIdx.x;
    if (e >= E) return;
    int dst = ei[E + e];
    int pos = atomicAdd(&cursor[dst], 1);
    csr[pos] = make_int2(ei[e], e);
}

// ========== fused GAT aggregation: 1 wave/node, 4 ch/lane, 2x unrolled ==========
__global__ __launch_bounds__(256) void gat_agg_kernel(
    const int* __restrict__ rowstart, const int2* __restrict__ csr,
    const float* __restrict__ p, const float* __restrict__ h, const float* __restrict__ bias,
    _Float16* __restrict__ Oh, _Float16* __restrict__ Ol, int H, int clog2)
{
    int node = blockIdx.x * 4 + (threadIdx.x >> 6);
    if (node >= N_NODES) return;
    int lane = threadIdx.x & 63;
    int c0 = lane * 4;
    int head = c0 >> clog2;
    int beg = rowstart[node], end = rowstart[node + 1];
    float ax0 = 0.f, ay0 = 0.f, az0 = 0.f, aw0 = 0.f, den0 = 0.f;
    float ax1 = 0.f, ay1 = 0.f, az1 = 0.f, aw1 = 0.f, den1 = 0.f;
    int i = beg;
    for (; i + 1 < end; i += 2) {
        int2 se0 = csr[i], se1 = csr[i + 1];
        float pv0 = p[(long)se0.y * H + head];
        float pv1 = p[(long)se1.y * H + head];
        const float4 h0 = *(const float4*)(h + (long)se0.x * NHC + c0);
        const float4 h1 = *(const float4*)(h + (long)se1.x * NHC + c0);
        den0 += pv0; den1 += pv1;
        ax0 += pv0 * h0.x; ay0 += pv0 * h0.y; az0 += pv0 * h0.z; aw0 += pv0 * h0.w;
        ax1 += pv1 * h1.x; ay1 += pv1 * h1.y; az1 += pv1 * h1.z; aw1 += pv1 * h1.w;
    }
    if (i < end) {
        int2 se = csr[i];
        float pv = p[(long)se.y * H + head];
        const float4 hv = *(const float4*)(h + (long)se.x * NHC + c0);
        den0 += pv;
        ax0 += pv * hv.x; ay0 += pv * hv.y; az0 += pv * hv.z; aw0 += pv * hv.w;
    }
    float den = den0 + den1;
    float w = 1.0f / (den + 1e-16f);
    const float4 bv = *(const float4*)(bias + c0);
    float4 v;
    v.x = (ax0 + ax1) * w + bv.x;  v.y = (ay0 + ay1) * w + bv.y;
    v.z = (az0 + az1) * w + bv.z;  v.w = (aw0 + aw1) * w + bv.w;
    v.x = (v.x > 0.f) ? v.x : expm1f(v.x);
    v.y = (v.y > 0.f) ? v.y : expm1f(v.y);
    v.z = (v.z > 0.f) ? v.z : expm1f(v.z);
    v.w = (v.w > 0.f) ? v.w : expm1f(v.w);
    f16x4 oh, ol;
    oh[0] = (_Float16)v.x; ol[0] = (_Float16)(v.x - (float)oh[0]);
    oh[1] = (_Float16)v.y; ol[1] = (_Float16)(v.y - (float)oh[1]);
    oh[2] = (_Float16)v.z; ol[2] = (_Float16)(v.z - (float)oh[2]);
    oh[3] = (_Float16)v.w; ol[3] = (_Float16)(v.w - (float)oh[3]);
    *(f16x4*)(Oh + (long)node * NHC + c0) = oh;
    *(f16x4*)(Ol + (long)node * NHC + c0) = ol;
}

// ================= pooling (batch sorted) =================
__global__ __launch_bounds__(256) void hist_kernel(
    const int* __restrict__ batch, int* __restrict__ gcnt, int N)
{
    __shared__ int hist[N_GRAPH];
    if (threadIdx.x < N_GRAPH) hist[threadIdx.x] = 0;
    __syncthreads();
    int i = blockIdx.x * 256 + threadIdx.x;
    if (i < N) atomicAdd(&hist[batch[i]], 1);
    __syncthreads();
    if (threadIdx.x < N_GRAPH && hist[threadIdx.x] > 0)
        atomicAdd(&gcnt[threadIdx.x], hist[threadIdx.x]);
}

__global__ void gstart_kernel(const int* __restrict__ gcnt, int* __restrict__ gstart)
{
    __shared__ int s[N_GRAPH];
    int t = threadIdx.x;
    int v = gcnt[t];
    s[t] = v;
    __syncthreads();
    for (int off = 1; off < N_GRAPH; off <<= 1) {
        int x = (t >= off) ? s[t - off] : 0;
        __syncthreads();
        s[t] += x;
        __syncthreads();
    }
    gstart[t] = s[t] - v;
    if (t == N_GRAPH - 1) gstart[N_GRAPH] = s[t];
}

__global__ __launch_bounds__(256) void pool_reduce_kernel(
    const float* __restrict__ f2, const int* __restrict__ gstart, float* __restrict__ out)
{
    __shared__ float red[8][32];
    int g = blockIdx.x;
    int c = threadIdx.x & 31, rsub = threadIdx.x >> 5;
    int beg = gstart[g], end = gstart[g + 1];
    float acc = 0.f;
    for (int row = beg + rsub; row < end; row += 8)
        acc += f2[(long)row * 32 + c];
    red[rsub][c] = acc;
    __syncthreads();
    if (rsub == 0) {
        float s = red[0][c] + red[1][c] + red[2][c] + red[3][c]
                + red[4][c] + red[5][c] + red[6][c] + red[7][c];
        out[g * 32 + c] = s / fmaxf((float)(end - beg), 1.0f);
    }
}

extern "C" void kernel_launch(void* const* d_in, const int* in_sizes, int n_in,
                              void* d_out, int out_size, void* d_ws, size_t ws_size,
                              hipStream_t stream)
{
    const float* x    = (const float*)d_in[0];
    const int*   ei   = (const int*)  d_in[1];
    const float* ea   = (const float*)d_in[2];
    const int*   bat  = (const int*)  d_in[3];
    const float* W[3]   = {(const float*)d_in[4],  (const float*)d_in[10], (const float*)d_in[16]};
    const float* Asl[3] = {(const float*)d_in[5],  (const float*)d_in[11], (const float*)d_in[17]};
    const float* Adl[3] = {(const float*)d_in[6],  (const float*)d_in[12], (const float*)d_in[18]};
    const float* Wel[3] = {(const float*)d_in[7],  (const float*)d_in[13], (const float*)d_in[19]};
    const float* Ael[3] = {(const float*)d_in[8],  (const float*)d_in[14], (const float*)d_in[20]};
    const float* Bil[3] = {(const float*)d_in[9],  (const float*)d_in[15], (const float*)d_in[21]};
    const float* fcW1 = (const float*)d_in[22];
    const float* fcb1 = (const float*)d_in[23];
    const float* fcW2 = (const float*)d_in[24];
    const float* fcb2 = (const float*)d_in[25];

    // ---- workspace carve (bytes) ----
    char* w = (char*)d_ws;
    float*    h    = (float*)w;        w += (size_t)N_NODES * NHC * 4;   // reused as f1 planes
    _Float16* xh   = (_Float16*)w;     w += (size_t)N_NODES * DIN * 2;
    _Float16* xl   = (_Float16*)w;     w += (size_t)N_NODES * DIN * 2;
    _Float16* xbh  = (_Float16*)w;     w += (size_t)N_NODES * NHC * 2;
    _Float16* xbl  = (_Float16*)w;     w += (size_t)N_NODES * NHC * 2;
    float*    f2   = (float*)w;        w += (size_t)N_NODES * DOUT * 4;
    float*    asb  = (float*)w;        w += (size_t)N_NODES * 8 * 4;
    float*    adb  = (float*)w;        w += (size_t)N_NODES * 8 * 4;
    float*    pbuf = (float*)w;        w += (size_t)N_EDGES * 8 * 4;
    float*    Me   = (float*)w;        w += 64 * 4;
    _Float16* W1th = (_Float16*)w;     w += (size_t)NHC * DIN * 2;
    _Float16* W1tl = (_Float16*)w;     w += (size_t)NHC * DIN * 2;
    _Float16* W2th = (_Float16*)w;     w += (size_t)NHC * NHC * 2;
    _Float16* W2tl = (_Float16*)w;     w += (size_t)NHC * NHC * 2;
    _Float16* W3th = (_Float16*)w;     w += (size_t)NHC * NHC * 2;
    _Float16* W3tl = (_Float16*)w;     w += (size_t)NHC * NHC * 2;
    _Float16* F1th = (_Float16*)w;     w += (size_t)NHC * NHC * 2;
    _Float16* F1tl = (_Float16*)w;     w += (size_t)NHC * NHC * 2;
    _Float16* F2th = (_Float16*)w;     w += (size_t)128 * NHC * 2;       // padded to 128 cols
    _Float16* F2tl = (_Float16*)w;     w += (size_t)128 * NHC * 2;
    int* gcnt     = (int*)w;           w += N_GRAPH * 4;
    int* gstart   = (int*)w;           w += (N_GRAPH + 1) * 4;
    int* deg      = (int*)w;           w += (size_t)N_NODES * 4;
    int* rowstart = (int*)w;           w += (size_t)(N_NODES + 1) * 4;
    int* cursor   = (int*)w;           w += (size_t)N_NODES * 4;
    int* partial  = (int*)w;           w += 256 * 4;
    w = (char*)(((size_t)w + 15) & ~(size_t)15);
    int2* csr     = (int2*)w;          w += (size_t)N_EDGES * 8;
    _Float16* f1h = (_Float16*)h;
    _Float16* f1l = f1h + (size_t)N_NODES * NHC;

    const int NB = (N_NODES + 255) / 256;

    // ---- prep: splits ----
    split_kernel<<<(N_NODES * DIN / 4 + 255) / 256, 256, 0, stream>>>(x, xh, xl, N_NODES * DIN / 4);
    tsplit_kernel<<<(NHC * DIN + 255) / 256, 256, 0, stream>>>(W[0], W1th, W1tl, DIN, NHC, NHC);
    tsplit_kernel<<<(NHC * NHC + 255) / 256, 256, 0, stream>>>(W[1], W2th, W2tl, NHC, NHC, NHC);
    tsplit_kernel<<<(NHC * NHC + 255) / 256, 256, 0, stream>>>(W[2], W3th, W3tl, NHC, NHC, NHC);
    tsplit_kernel<<<(NHC * NHC + 255) / 256, 256, 0, stream>>>(fcW1, F1th, F1tl, NHC, NHC, NHC);
    tsplit_kernel<<<(128 * NHC + 255) / 256, 256, 0, stream>>>(fcW2, F2th, F2tl, NHC, DOUT, 128);

    // ---- CSR build ----
    hipMemsetAsync(deg, 0, (size_t)N_NODES * 4, stream);
    count_kernel<<<(N_EDGES + 255) / 256, 256, 0, stream>>>(ei, deg, N_EDGES);
    scan_block_kernel<<<NB, 256, 0, stream>>>(deg, rowstart, partial, N_NODES);
    scan_partial_kernel<<<1, 256, 0, stream>>>(partial, NB);
    scan_add_kernel<<<NB, 256, 0, stream>>>(rowstart, partial, cursor, N_NODES, N_EDGES);
    fill_kernel<<<(N_EDGES + 255) / 256, 256, 0, stream>>>(ei, cursor, csr, N_EDGES);

    // ---- graph ranges for pooling ----
    hipMemsetAsync(gcnt, 0, N_GRAPH * 4, stream);
    hist_kernel<<<NB, 256, 0, stream>>>(bat, gcnt, N_NODES);
    gstart_kernel<<<1, N_GRAPH, 0, stream>>>(gcnt, gstart);

    const int Hs[3] = {8, 8, 1};
    const int Cs[3] = {32, 32, 256};
    const int CL[3] = {5, 5, 8};
    const int Ks[3] = {DIN, NHC, NHC};

    const dim3 ggrid(2, 392);               // Y padded to %8 for the swizzle bijection

    const _Float16* curh = xh;
    const _Float16* curl = xl;
    const _Float16* Wth[3] = {W1th, W2th, W3th};
    const _Float16* Wtl[3] = {W1tl, W2tl, W3tl};
    for (int l = 0; l < 3; l++) {
        const int H = Hs[l], C = Cs[l];
        const int nh = N_NODES * H;
        mfma_gemm_kernel<<<ggrid, 256, 0, stream>>>(
            curh, curl, Wth[l], Wtl[l], nullptr, h, nullptr, nullptr,
            N_NODES, Ks[l], NHC, 0);
        asd_kernel<<<(nh + 255) / 256, 256, 0, stream>>>(h, Asl[l], Adl[l], asb, adb, nh, H, C);
        me_kernel<<<1, 64, 0, stream>>>(Wel[l], Ael[l], Me, H, C);
        edge_p_kernel<<<(N_EDGES + 255) / 256, 256, 0, stream>>>(ei, ea, asb, adb, Me, pbuf, N_EDGES, H);
        gat_agg_kernel<<<(N_NODES + 3) / 4, 256, 0, stream>>>(
            rowstart, csr, pbuf, h, Bil[l], xbh, xbl, H, CL[l]);
        curh = xbh; curl = xbl;
    }

    // fc1: gelu(xb @ fcW1 + b) -> f1 planes (overlays dead h)
    mfma_gemm_kernel<<<ggrid, 256, 0, stream>>>(
        xbh, xbl, F1th, F1tl, fcb1, nullptr, f1h, f1l, N_NODES, NHC, NHC, 1);
    // fc2: f1 @ fcW2 + b -> f2 fp32 (cols masked to 32)
    const dim3 g2(1, (N_NODES + 127) / 128);
    mfma_gemm_kernel<<<g2, 256, 0, stream>>>(
        f1h, f1l, F2th, F2tl, fcb2, f2, nullptr, nullptr, N_NODES, NHC, DOUT, 2);

    // pooling
    pool_reduce_kernel<<<N_GRAPH, 256, 0, stream>>>(f2, gstart, (float*)d_out);
}

// Round 6
// 714.363 us; speedup vs baseline: 1.0724x; 1.0724x over previous
//
#include <hip/hip_runtime.h>
#include <math.h>

// GATNet_MLP R6: back to 128x64 GEMM tile (6 blocks/CU vs R5's grid-limited 3)
// + register-prefetch software pipeline (global load of tile k+1 issued after the
// barrier, overlapping the MFMA phase of tile k). LDP=40 pad + XCD swizzle kept
// (R5 verified: FETCH 170->27MB). gat_agg/edge_p/CSR/pool unchanged from R5.

#define N_NODES 50000
#define N_EDGES 400000
#define N_GRAPH 64
#define DIN     128
#define NHC     256
#define DOUT    32

typedef _Float16 f16x8 __attribute__((ext_vector_type(8)));
typedef _Float16 f16x4 __attribute__((ext_vector_type(4)));
typedef float    f32x4 __attribute__((ext_vector_type(4)));

#define LDP 40   // padded LDS row stride in halfs (80B)

// ================= fp16x2-split MFMA GEMM, 128x64 tile, pipelined =================
// A planes [nrow][K], B planes [Npad][K] transposed. mode 0: C fp32 [nrow][256];
// mode 1: bias+gelu -> fp16 planes; mode 2: bias -> fp32 C [nrow][ncols] masked.
__global__ __launch_bounds__(256) void mfma_gemm_kernel(
    const _Float16* __restrict__ Ah, const _Float16* __restrict__ Al,
    const _Float16* __restrict__ Bh, const _Float16* __restrict__ Bl,
    const float* __restrict__ bias, float* __restrict__ C,
    _Float16* __restrict__ Oh, _Float16* __restrict__ Ol,
    int nrow, int K, int ncols, int mode)
{
    __shared__ __align__(16) _Float16 sAh[128][LDP];
    __shared__ __align__(16) _Float16 sAl[128][LDP];
    __shared__ __align__(16) _Float16 sBh[64][LDP];
    __shared__ __align__(16) _Float16 sBl[64][LDP];

    const int tid = threadIdx.x, lane = tid & 63, wid = tid >> 6;
    const int wm = wid & 1, wn = wid >> 1;

    // XCD-aware swizzle (gridX==4): bids {b5*32 + xt*8 + r} share XCD slot r mod 8;
    // the 4 col-tiles of row-block yt land on one XCD -> A row-block L2-resident.
    int xt, yt;
    if (gridDim.x == 4) {
        int bid = blockIdx.x + (blockIdx.y << 2);
        yt = (bid >> 5) * 8 + (bid & 7);
        xt = (bid >> 3) & 3;
    } else { xt = blockIdx.x; yt = blockIdx.y; }
    const int row0 = yt * 128, col0 = xt * 64;
    if (row0 >= nrow) return;                 // pad blocks exit (uniform)

    const int frow = lane & 15, fk = (lane >> 4) * 8;
    const int ra = tid >> 2, kq = (tid & 3) * 8;   // staging: rows 0..63, 4 chunks

    f32x4 acc[4][2] = {};
    f16x8 pAh[2], pAl[2], pBh, pBl;

    // prefetch tile 0
    {
#pragma unroll
        for (int p = 0; p < 2; p++) {
            int gr = row0 + p * 64 + ra;
            long go = (long)gr * K + kq;
            pAh[p] = (gr < nrow) ? *(const f16x8*)(Ah + go) : (f16x8)0;
            pAl[p] = (gr < nrow) ? *(const f16x8*)(Al + go) : (f16x8)0;
        }
        long gob = (long)(col0 + ra) * K + kq;
        pBh = *(const f16x8*)(Bh + gob);
        pBl = *(const f16x8*)(Bl + gob);
    }

    for (int k0 = 0; k0 < K; k0 += 32) {
        // drain prefetch regs -> LDS
#pragma unroll
        for (int p = 0; p < 2; p++) {
            *(f16x8*)&sAh[p * 64 + ra][kq] = pAh[p];
            *(f16x8*)&sAl[p * 64 + ra][kq] = pAl[p];
        }
        *(f16x8*)&sBh[ra][kq] = pBh;
        *(f16x8*)&sBl[ra][kq] = pBl;
        __syncthreads();

        // issue next tile's global loads NOW; they complete during the MFMA phase
        if (k0 + 32 < K) {
            int kn = k0 + 32 + kq;
#pragma unroll
            for (int p = 0; p < 2; p++) {
                int gr = row0 + p * 64 + ra;
                long go = (long)gr * K + kn;
                pAh[p] = (gr < nrow) ? *(const f16x8*)(Ah + go) : (f16x8)0;
                pAl[p] = (gr < nrow) ? *(const f16x8*)(Al + go) : (f16x8)0;
            }
            long gob = (long)(col0 + ra) * K + kn;
            pBh = *(const f16x8*)(Bh + gob);
            pBl = *(const f16x8*)(Bl + gob);
        }

        // MFMA phase (reads LDS only)
        f16x8 bh[2], bl[2];
#pragma unroll
        for (int nt = 0; nt < 2; nt++) {
            bh[nt] = *(const f16x8*)&sBh[wn * 32 + nt * 16 + frow][fk];
            bl[nt] = *(const f16x8*)&sBl[wn * 32 + nt * 16 + frow][fk];
        }
#pragma unroll
        for (int mt = 0; mt < 4; mt++) {
            f16x8 ah = *(const f16x8*)&sAh[wm * 64 + mt * 16 + frow][fk];
            f16x8 al = *(const f16x8*)&sAl[wm * 64 + mt * 16 + frow][fk];
#pragma unroll
            for (int nt = 0; nt < 2; nt++) {
                acc[mt][nt] = __builtin_amdgcn_mfma_f32_16x16x32_f16(ah, bh[nt], acc[mt][nt], 0, 0, 0);
                acc[mt][nt] = __builtin_amdgcn_mfma_f32_16x16x32_f16(ah, bl[nt], acc[mt][nt], 0, 0, 0);
                acc[mt][nt] = __builtin_amdgcn_mfma_f32_16x16x32_f16(al, bh[nt], acc[mt][nt], 0, 0, 0);
            }
        }
        __syncthreads();
    }

    // epilogue: C/D layout col=lane&15, row=(lane>>4)*4+reg
    const int crow0 = row0 + wm * 64 + (lane >> 4) * 4;
    const int ccol0 = col0 + wn * 32 + (lane & 15);
#pragma unroll
    for (int mt = 0; mt < 4; mt++) {
#pragma unroll
        for (int nt = 0; nt < 2; nt++) {
            int col = ccol0 + nt * 16;
#pragma unroll
            for (int r = 0; r < 4; r++) {
                int row = crow0 + mt * 16 + r;
                if (row >= nrow) continue;
                float v = acc[mt][nt][r];
                if (mode == 0) {
                    C[(long)row * 256 + col] = v;
                } else if (mode == 1) {
                    v += bias[col];
                    v = 0.5f * v * (1.f + erff(v * 0.7071067811865475f));
                    _Float16 hh = (_Float16)v;
                    Oh[(long)row * 256 + col] = hh;
                    Ol[(long)row * 256 + col] = (_Float16)(v - (float)hh);
                } else {
                    if (col < ncols) {
                        v += bias[col];
                        C[(long)row * ncols + col] = v;
                    }
                }
            }
        }
    }
}

// -------- split fp32 -> fp16 hi/lo planes --------
__global__ __launch_bounds__(256) void split_kernel(
    const float* __restrict__ in, _Float16* __restrict__ oh, _Float16* __restrict__ ol, int n4)
{
    int i = blockIdx.x * 256 + threadIdx.x;
    if (i >= n4) return;
    float4 v = ((const float4*)in)[i];
    f16x4 h, l;
    h[0] = (_Float16)v.x; l[0] = (_Float16)(v.x - (float)h[0]);
    h[1] = (_Float16)v.y; l[1] = (_Float16)(v.y - (float)h[1]);
    h[2] = (_Float16)v.z; l[2] = (_Float16)(v.z - (float)h[2]);
    h[3] = (_Float16)v.w; l[3] = (_Float16)(v.w - (float)h[3]);
    *(f16x4*)(oh + (long)i * 4) = h;
    *(f16x4*)(ol + (long)i * 4) = l;
}

// -------- transpose + split weights: W[K][N] fp32 -> planes [Npad][K] --------
__global__ __launch_bounds__(256) void tsplit_kernel(
    const float* __restrict__ W, _Float16* __restrict__ Bh, _Float16* __restrict__ Bl,
    int K, int N, int Npad)
{
    int id = blockIdx.x * 256 + threadIdx.x;
    if (id >= Npad * K) return;
    int n = id / K, k = id - n * K;
    float v = (n < N) ? W[(long)k * N + n] : 0.f;
    _Float16 h = (_Float16)v;
    Bh[id] = h;
    Bl[id] = (_Float16)(v - (float)h);
}

// -------- per-node attention scalars --------
__global__ __launch_bounds__(256) void asd_kernel(
    const float* __restrict__ h, const float* __restrict__ atts, const float* __restrict__ attd,
    float* __restrict__ asb, float* __restrict__ adb, int total, int H, int C)
{
    int i = blockIdx.x * 256 + threadIdx.x;
    if (i >= total) return;
    int n = i / H, hh = i - n * H;
    const float4* hp = (const float4*)(h + (long)n * NHC + hh * C);
    const float4* sp = (const float4*)(atts + hh * C);
    const float4* dp = (const float4*)(attd + hh * C);
    float ss = 0.f, dd = 0.f;
    for (int c = 0; c < C / 4; c++) {
        float4 hv = hp[c], sv = sp[c], dv = dp[c];
        ss += hv.x * sv.x + hv.y * sv.y + hv.z * sv.z + hv.w * sv.w;
        dd += hv.x * dv.x + hv.y * dv.y + hv.z * dv.z + hv.w * dv.w;
    }
    asb[i] = ss; adb[i] = dd;
}

// -------- Me[j,h] = sum_c We[j, h*C+c] * ae[h*C+c] --------
__global__ void me_kernel(const float* __restrict__ We, const float* __restrict__ ae,
                          float* __restrict__ Me, int H, int C)
{
    int i = threadIdx.x;
    if (i >= 5 * H) return;
    int j = i / H, hh = i - j * H;
    float s = 0.f;
    for (int c = 0; c < C; c++) s += We[j * NHC + hh * C + c] * ae[hh * C + c];
    Me[i] = s;
}

// -------- edge-parallel p --------
__global__ __launch_bounds__(256) void edge_p_kernel(
    const int* __restrict__ ei, const float* __restrict__ ea,
    const float* __restrict__ asb, const float* __restrict__ adb,
    const float* __restrict__ Me, float* __restrict__ p, int E, int H)
{
    int e = blockIdx.x * 256 + threadIdx.x;
    if (e >= E) return;
    int src = ei[e], dst = ei[E + e];
    float a0 = ea[e * 5 + 0], a1 = ea[e * 5 + 1], a2 = ea[e * 5 + 2],
          a3 = ea[e * 5 + 3], a4 = ea[e * 5 + 4];
    for (int h = 0; h < H; h++) {
        float aeh = a0 * Me[0 * H + h] + a1 * Me[1 * H + h] + a2 * Me[2 * H + h]
                  + a3 * Me[3 * H + h] + a4 * Me[4 * H + h];
        float al = asb[src * H + h] + adb[dst * H + h] + aeh;
        al = fmaxf(al, 0.2f * al);
        p[(long)e * H + h] = expf(al);
    }
}

// ================= CSR build (entries packed int2{src,eid}) =================
__global__ __launch_bounds__(256) void count_kernel(
    const int* __restrict__ ei, int* __restrict__ deg, int E)
{
    int e = blockIdx.x * 256 + threadIdx.x;
    if (e < E) atomicAdd(&deg[ei[E + e]], 1);
}

__global__ __launch_bounds__(256) void scan_block_kernel(
    const int* __restrict__ deg, int* __restrict__ rowstart, int* __restrict__ partial, int n)
{
    __shared__ int s[256];
    int i = blockIdx.x * 256 + threadIdx.x;
    int v = (i < n) ? deg[i] : 0;
    s[threadIdx.x] = v;
    __syncthreads();
    for (int off = 1; off < 256; off <<= 1) {
        int t = (threadIdx.x >= off) ? s[threadIdx.x - off] : 0;
        __syncthreads();
        s[threadIdx.x] += t;
        __syncthreads();
    }
    if (i < n) rowstart[i] = s[threadIdx.x] - v;
    if (threadIdx.x == 255) partial[blockIdx.x] = s[255];
}

__global__ __launch_bounds__(256) void scan_partial_kernel(int* __restrict__ partial, int nb)
{
    __shared__ int s[256];
    int v = (threadIdx.x < nb) ? partial[threadIdx.x] : 0;
    s[threadIdx.x] = v;
    __syncthreads();
    for (int off = 1; off < 256; off <<= 1) {
        int t = (threadIdx.x >= off) ? s[threadIdx.x - off] : 0;
        __syncthreads();
        s[threadIdx.x] += t;
        __syncthreads();
    }
    if (threadIdx.x < nb) partial[threadIdx.x] = s[threadIdx.x] - v;
}

__global__ __launch_bounds__(256) void scan_add_kernel(
    int* __restrict__ rowstart, const int* __restrict__ partial, int* __restrict__ cursor,
    int n, int E)
{
    int i = blockIdx.x * 256 + threadIdx.x;
    if (i < n) {
        int v = rowstart[i] + partial[blockIdx.x];
        rowstart[i] = v;
        cursor[i] = v;
    }
    if (i == 0) rowstart[n] = E;
}

__global__ __launch_bounds__(256) void fill_kernel(
    const int* __restrict__ ei, int* __restrict__ cursor, int2* __restrict__ csr, int E)
{
    int e = blockIdx.x * 256 + threadIdx.x;
    if (e >= E) return;
    int dst = ei[E + e];
    int pos = atomicAdd(&cursor[dst], 1);
    csr[pos] = make_int2(ei[e], e);
}

// ========== fused GAT aggregation: 1 wave/node, 4 ch/lane, 2x unrolled ==========
__global__ __launch_bounds__(256) void gat_agg_kernel(
    const int* __restrict__ rowstart, const int2* __restrict__ csr,
    const float* __restrict__ p, const float* __restrict__ h, const float* __restrict__ bias,
    _Float16* __restrict__ Oh, _Float16* __restrict__ Ol, int H, int clog2)
{
    int node = blockIdx.x * 4 + (threadIdx.x >> 6);
    if (node >= N_NODES) return;
    int lane = threadIdx.x & 63;
    int c0 = lane * 4;
    int head = c0 >> clog2;
    int beg = rowstart[node], end = rowstart[node + 1];
    float ax0 = 0.f, ay0 = 0.f, az0 = 0.f, aw0 = 0.f, den0 = 0.f;
    float ax1 = 0.f, ay1 = 0.f, az1 = 0.f, aw1 = 0.f, den1 = 0.f;
    int i = beg;
    for (; i + 1 < end; i += 2) {
        int2 se0 = csr[i], se1 = csr[i + 1];
        float pv0 = p[(long)se0.y * H + head];
        float pv1 = p[(long)se1.y * H + head];
        const float4 h0 = *(const float4*)(h + (long)se0.x * NHC + c0);
        const float4 h1 = *(const float4*)(h + (long)se1.x * NHC + c0);
        den0 += pv0; den1 += pv1;
        ax0 += pv0 * h0.x; ay0 += pv0 * h0.y; az0 += pv0 * h0.z; aw0 += pv0 * h0.w;
        ax1 += pv1 * h1.x; ay1 += pv1 * h1.y; az1 += pv1 * h1.z; aw1 += pv1 * h1.w;
    }
    if (i < end) {
        int2 se = csr[i];
        float pv = p[(long)se.y * H + head];
        const float4 hv = *(const float4*)(h + (long)se.x * NHC + c0);
        den0 += pv;
        ax0 += pv * hv.x; ay0 += pv * hv.y; az0 += pv * hv.z; aw0 += pv * hv.w;
    }
    float den = den0 + den1;
    float w = 1.0f / (den + 1e-16f);
    const float4 bv = *(const float4*)(bias + c0);
    float4 v;
    v.x = (ax0 + ax1) * w + bv.x;  v.y = (ay0 + ay1) * w + bv.y;
    v.z = (az0 + az1) * w + bv.z;  v.w = (aw0 + aw1) * w + bv.w;
    v.x = (v.x > 0.f) ? v.x : expm1f(v.x);
    v.y = (v.y > 0.f) ? v.y : expm1f(v.y);
    v.z = (v.z > 0.f) ? v.z : expm1f(v.z);
    v.w = (v.w > 0.f) ? v.w : expm1f(v.w);
    f16x4 oh, ol;
    oh[0] = (_Float16)v.x; ol[0] = (_Float16)(v.x - (float)oh[0]);
    oh[1] = (_Float16)v.y; ol[1] = (_Float16)(v.y - (float)oh[1]);
    oh[2] = (_Float16)v.z; ol[2] = (_Float16)(v.z - (float)oh[2]);
    oh[3] = (_Float16)v.w; ol[3] = (_Float16)(v.w - (float)oh[3]);
    *(f16x4*)(Oh + (long)node * NHC + c0) = oh;
    *(f16x4*)(Ol + (long)node * NHC + c0) = ol;
}

// ================= pooling (batch sorted) =================
__global__ __launch_bounds__(256) void hist_kernel(
    const int* __restrict__ batch, int* __restrict__ gcnt, int N)
{
    __shared__ int hist[N_GRAPH];
    if (threadIdx.x < N_GRAPH) hist[threadIdx.x] = 0;
    __syncthreads();
    int i = blockIdx.x * 256 + threadIdx.x;
    if (i < N) atomicAdd(&hist[batch[i]], 1);
    __syncthreads();
    if (threadIdx.x < N_GRAPH && hist[threadIdx.x] > 0)
        atomicAdd(&gcnt[threadIdx.x], hist[threadIdx.x]);
}

__global__ void gstart_kernel(const int* __restrict__ gcnt, int* __restrict__ gstart)
{
    __shared__ int s[N_GRAPH];
    int t = threadIdx.x;
    int v = gcnt[t];
    s[t] = v;
    __syncthreads();
    for (int off = 1; off < N_GRAPH; off <<= 1) {
        int x = (t >= off) ? s[t - off] : 0;
        __syncthreads();
        s[t] += x;
        __syncthreads();
    }
    gstart[t] = s[t] - v;
    if (t == N_GRAPH - 1) gstart[N_GRAPH] = s[t];
}

__global__ __launch_bounds__(256) void pool_reduce_kernel(
    const float* __restrict__ f2, const int* __restrict__ gstart, float* __restrict__ out)
{
    __shared__ float red[8][32];
    int g = blockIdx.x;
    int c = threadIdx.x & 31, rsub = threadIdx.x >> 5;
    int beg = gstart[g], end = gstart[g + 1];
    float acc = 0.f;
    for (int row = beg + rsub; row < end; row += 8)
        acc += f2[(long)row * 32 + c];
    red[rsub][c] = acc;
    __syncthreads();
    if (rsub == 0) {
        float s = red[0][c] + red[1][c] + red[2][c] + red[3][c]
                + red[4][c] + red[5][c] + red[6][c] + red[7][c];
        out[g * 32 + c] = s / fmaxf((float)(end - beg), 1.0f);
    }
}

extern "C" void kernel_launch(void* const* d_in, const int* in_sizes, int n_in,
                              void* d_out, int out_size, void* d_ws, size_t ws_size,
                              hipStream_t stream)
{
    const float* x    = (const float*)d_in[0];
    const int*   ei   = (const int*)  d_in[1];
    const float* ea   = (const float*)d_in[2];
    const int*   bat  = (const int*)  d_in[3];
    const float* W[3]   = {(const float*)d_in[4],  (const float*)d_in[10], (const float*)d_in[16]};
    const float* Asl[3] = {(const float*)d_in[5],  (const float*)d_in[11], (const float*)d_in[17]};
    const float* Adl[3] = {(const float*)d_in[6],  (const float*)d_in[12], (const float*)d_in[18]};
    const float* Wel[3] = {(const float*)d_in[7],  (const float*)d_in[13], (const float*)d_in[19]};
    const float* Ael[3] = {(const float*)d_in[8],  (const float*)d_in[14], (const float*)d_in[20]};
    const float* Bil[3] = {(const float*)d_in[9],  (const float*)d_in[15], (const float*)d_in[21]};
    const float* fcW1 = (const float*)d_in[22];
    const float* fcb1 = (const float*)d_in[23];
    const float* fcW2 = (const float*)d_in[24];
    const float* fcb2 = (const float*)d_in[25];

    // ---- workspace carve (bytes) ----
    char* w = (char*)d_ws;
    float*    h    = (float*)w;        w += (size_t)N_NODES * NHC * 4;   // reused as f1 planes
    _Float16* xh   = (_Float16*)w;     w += (size_t)N_NODES * DIN * 2;
    _Float16* xl   = (_Float16*)w;     w += (size_t)N_NODES * DIN * 2;
    _Float16* xbh  = (_Float16*)w;     w += (size_t)N_NODES * NHC * 2;
    _Float16* xbl  = (_Float16*)w;     w += (size_t)N_NODES * NHC * 2;
    float*    f2   = (float*)w;        w += (size_t)N_NODES * DOUT * 4;
    float*    asb  = (float*)w;        w += (size_t)N_NODES * 8 * 4;
    float*    adb  = (float*)w;        w += (size_t)N_NODES * 8 * 4;
    float*    pbuf = (float*)w;        w += (size_t)N_EDGES * 8 * 4;
    float*    Me   = (float*)w;        w += 64 * 4;
    _Float16* W1th = (_Float16*)w;     w += (size_t)NHC * DIN * 2;
    _Float16* W1tl = (_Float16*)w;     w += (size_t)NHC * DIN * 2;
    _Float16* W2th = (_Float16*)w;     w += (size_t)NHC * NHC * 2;
    _Float16* W2tl = (_Float16*)w;     w += (size_t)NHC * NHC * 2;
    _Float16* W3th = (_Float16*)w;     w += (size_t)NHC * NHC * 2;
    _Float16* W3tl = (_Float16*)w;     w += (size_t)NHC * NHC * 2;
    _Float16* F1th = (_Float16*)w;     w += (size_t)NHC * NHC * 2;
    _Float16* F1tl = (_Float16*)w;     w += (size_t)NHC * NHC * 2;
    _Float16* F2th = (_Float16*)w;     w += (size_t)128 * NHC * 2;
    _Float16* F2tl = (_Float16*)w;     w += (size_t)128 * NHC * 2;
    int* gcnt     = (int*)w;           w += N_GRAPH * 4;
    int* gstart   = (int*)w;           w += (N_GRAPH + 1) * 4;
    int* deg      = (int*)w;           w += (size_t)N_NODES * 4;
    int* rowstart = (int*)w;           w += (size_t)(N_NODES + 1) * 4;
    int* cursor   = (int*)w;           w += (size_t)N_NODES * 4;
    int* partial  = (int*)w;           w += 256 * 4;
    w = (char*)(((size_t)w + 15) & ~(size_t)15);
    int2* csr     = (int2*)w;          w += (size_t)N_EDGES * 8;
    _Float16* f1h = (_Float16*)h;
    _Float16* f1l = f1h + (size_t)N_NODES * NHC;

    const int NB = (N_NODES + 255) / 256;

    // ---- prep: splits ----
    split_kernel<<<(N_NODES * DIN / 4 + 255) / 256, 256, 0, stream>>>(x, xh, xl, N_NODES * DIN / 4);
    tsplit_kernel<<<(NHC * DIN + 255) / 256, 256, 0, stream>>>(W[0], W1th, W1tl, DIN, NHC, NHC);
    tsplit_kernel<<<(NHC * NHC + 255) / 256, 256, 0, stream>>>(W[1], W2th, W2tl, NHC, NHC, NHC);
    tsplit_kernel<<<(NHC * NHC + 255) / 256, 256, 0, stream>>>(W[2], W3th, W3tl, NHC, NHC, NHC);
    tsplit_kernel<<<(NHC * NHC + 255) / 256, 256, 0, stream>>>(fcW1, F1th, F1tl, NHC, NHC, NHC);
    tsplit_kernel<<<(128 * NHC + 255) / 256, 256, 0, stream>>>(fcW2, F2th, F2tl, NHC, DOUT, 128);

    // ---- CSR build ----
    hipMemsetAsync(deg, 0, (size_t)N_NODES * 4, stream);
    count_kernel<<<(N_EDGES + 255) / 256, 256, 0, stream>>>(ei, deg, N_EDGES);
    scan_block_kernel<<<NB, 256, 0, stream>>>(deg, rowstart, partial, N_NODES);
    scan_partial_kernel<<<1, 256, 0, stream>>>(partial, NB);
    scan_add_kernel<<<NB, 256, 0, stream>>>(rowstart, partial, cursor, N_NODES, N_EDGES);
    fill_kernel<<<(N_EDGES + 255) / 256, 256, 0, stream>>>(ei, cursor, csr, N_EDGES);

    // ---- graph ranges for pooling ----
    hipMemsetAsync(gcnt, 0, N_GRAPH * 4, stream);
    hist_kernel<<<NB, 256, 0, stream>>>(bat, gcnt, N_NODES);
    gstart_kernel<<<1, N_GRAPH, 0, stream>>>(gcnt, gstart);

    const int Hs[3] = {8, 8, 1};
    const int Cs[3] = {32, 32, 256};
    const int CL[3] = {5, 5, 8};

    const dim3 ggrid(4, 392);               // 1568 blocks; Y padded %8 for swizzle

    const _Float16* curh = xh;
    const _Float16* curl = xl;
    const _Float16* Wth[3] = {W1th, W2th, W3th};
    const _Float16* Wtl[3] = {W1tl, W2tl, W3tl};
    const int Ks[3] = {DIN, NHC, NHC};
    for (int l = 0; l < 3; l++) {
        const int H = Hs[l], C = Cs[l];
        const int nh = N_NODES * H;
        mfma_gemm_kernel<<<ggrid, 256, 0, stream>>>(
            curh, curl, Wth[l], Wtl[l], nullptr, h, nullptr, nullptr,
            N_NODES, Ks[l], NHC, 0);
        asd_kernel<<<(nh + 255) / 256, 256, 0, stream>>>(h, Asl[l], Adl[l], asb, adb, nh, H, C);
        me_kernel<<<1, 64, 0, stream>>>(Wel[l], Ael[l], Me, H, C);
        edge_p_kernel<<<(N_EDGES + 255) / 256, 256, 0, stream>>>(ei, ea, asb, adb, Me, pbuf, N_EDGES, H);
        gat_agg_kernel<<<(N_NODES + 3) / 4, 256, 0, stream>>>(
            rowstart, csr, pbuf, h, Bil[l], xbh, xbl, H, CL[l]);
        curh = xbh; curl = xbl;
    }

    // fc1: gelu(xb @ fcW1 + b) -> f1 planes (overlays dead h)
    mfma_gemm_kernel<<<ggrid, 256, 0, stream>>>(
        xbh, xbl, F1th, F1tl, fcb1, nullptr, f1h, f1l, N_NODES, NHC, NHC, 1);
    // fc2: f1 @ fcW2 + b -> f2 fp32 (tile covers cols 0..63, masked to 32)
    const dim3 g2(1, (N_NODES + 127) / 128);
    mfma_gemm_kernel<<<g2, 256, 0, stream>>>(
        f1h, f1l, F2th, F2tl, fcb2, f2, nullptr, nullptr, N_NODES, NHC, DOUT, 2);

    // pooling
    pool_reduce_kernel<<<N_GRAPH, 256, 0, stream>>>(f2, gstart, (float*)d_out);
}